// Round 9
// baseline (5075.958 us; speedup 1.0000x reference)
//
#include <hip/hip_runtime.h>
#include <cstdint>
#include <cstddef>

// Problem constants (inputs are FLOAT32; output float32)
#define BATCH   2048
#define EMB     1024
#define HEADS   8
#define HDIM    128
#define TOPK    10
#define MEMN    100000
#define NTILES  782          // ceil(100000/128)  (BN=128 col tiles)
#define CHUNKS  64
#define TPC     13           // 64*13 = 832 >= 782
#define CAND    20           // rescored candidate count
#define SCALE   0.08838834764831845f

// TOOLCHAIN LAW (measured R1-R7): hipcc allocates ~1024/(waves-per-block)
// VGPRs regardless of __launch_bounds__ 2nd arg. 8 waves -> ~128 cap;
// acc 64/wave + modest state fits (R4: 120, no spill). Exceed it and acc
// spills to scratch (R3/R5/R6: WRITE_SIZE 10MB -> 1.4-17GB).
// OCCUPANCY LAW (R4/R8 vs m97/m114): 1 block/CU means every barrier
// stalls the whole CU; cross-block overlap needs >=2 blocks/CU. This
// round: 48 KB LDS -> 2 blocks/CU co-resident.

typedef _Float16 h16;
typedef _Float16 half8 __attribute__((ext_vector_type(8)));
typedef _Float16 half4 __attribute__((ext_vector_type(4)));
typedef float    f32x4 __attribute__((ext_vector_type(4)));

// ---- async global->LDS, 16B per lane (wave-uniform LDS base + lane*16) ----
__device__ __forceinline__ void gl_lds16(const void* g, void* l) {
  __builtin_amdgcn_global_load_lds(
      (const __attribute__((address_space(1))) unsigned int*)g,
      (__attribute__((address_space(3))) unsigned int*)l, 16, 0, 0);
}

// ---- pipeline barriers (counted vmcnt: loads stay in flight across bar) ----
__device__ __forceinline__ void bar_sync() {   // barrier, NO vm drain
  asm volatile("" ::: "memory");
  __builtin_amdgcn_s_barrier();
  __builtin_amdgcn_sched_barrier(0);
}
__device__ __forceinline__ void bar_wait3() {  // wait all but newest 3 loads
  asm volatile("s_waitcnt vmcnt(3)" ::: "memory");
  __builtin_amdgcn_s_barrier();
  __builtin_amdgcn_sched_barrier(0);
}
__device__ __forceinline__ void bar_wait0() {  // full vm drain + barrier
  asm volatile("s_waitcnt vmcnt(0)" ::: "memory");
  __builtin_amdgcn_s_barrier();
  __builtin_amdgcn_sched_barrier(0);
}

// ---- register top-N insertion ----
template <int N>
__device__ __forceinline__ void topk_ins(float (&tv)[N], int (&ti)[N],
                                         float s, int gi) {
  float cv = s; int ci = gi;
#pragma unroll
  for (int j = 0; j < N; ++j) {
    bool sw = tv[j] < cv;
    float tf = tv[j]; int tt = ti[j];
    if (sw) { tv[j] = cv; ti[j] = ci; cv = tf; ci = tt; }
  }
}

// =====================================================================
// Conversion kernels
// =====================================================================
__global__ void __launch_bounds__(256) k_f2h(
    const float* __restrict__ in, h16* __restrict__ out, long n4)
{
  long i = (long)blockIdx.x * 256 + threadIdx.x;
  const long stride = (long)gridDim.x * 256;
  for (; i < n4; i += stride) {
    const f32x4 v = ((const f32x4*)in)[i];
    half4 o;
#pragma unroll
    for (int j = 0; j < 4; ++j) o[j] = (h16)v[j];
    ((half4*)out)[i] = o;
  }
}

// three 1024x1024 weight conversions in one launch (blockIdx.y selects)
__global__ void __launch_bounds__(256) k_f2h3(
    const float* __restrict__ a, const float* __restrict__ b,
    const float* __restrict__ c,
    h16* __restrict__ oa, h16* __restrict__ ob, h16* __restrict__ oc)
{
  const float* in = (blockIdx.y == 0) ? a : (blockIdx.y == 1) ? b : c;
  h16* out       = (blockIdx.y == 0) ? oa : (blockIdx.y == 1) ? ob : oc;
  const long i = (long)blockIdx.x * 256 + threadIdx.x;   // 0..262143
  const f32x4 v = ((const f32x4*)in)[i];
  half4 o;
#pragma unroll
  for (int j = 0; j < 4; ++j) o[j] = (h16)v[j];
  ((half4*)out)[i] = o;
}

// w_k [n][e] -> wkT fp16 [e][n], tiled via LDS (both sides coalesced)
__global__ void __launch_bounds__(256) k_f2hT(
    const float* __restrict__ in, h16* __restrict__ out)
{
  __shared__ float tl[64][65];
  const int n0 = blockIdx.x * 64, e0 = blockIdx.y * 64;
  const int cc = threadIdx.x & 63, rb = threadIdx.x >> 6;
#pragma unroll
  for (int i = 0; i < 16; ++i) {
    const int r = i * 4 + rb;
    tl[r][cc] = in[(size_t)(n0 + r) * EMB + e0 + cc];
  }
  __syncthreads();
#pragma unroll
  for (int i = 0; i < 16; ++i) {
    const int r = i * 4 + rb;        // e-local
    out[(size_t)(e0 + r) * EMB + n0 + cc] = (h16)tl[cc][r];
  }
}

// =====================================================================
// K1a helpers (fast path): BM=256 x BN=128 tile, 8 waves (4M x 2N),
// per-wave output 64x64 (acc = 64 VGPR), BK=32.
// LDS (48 KB): A0 [0,16K) A1 [16K,32K) B0 [32K,40K) B1 [40K,48K)
// 48 KB -> 2 blocks/CU co-resident (the m114 cross-block overlap).
// =====================================================================
__device__ __forceinline__ void sim_stage2(
    const h16* __restrict__ query, const h16* __restrict__ memory,
    char* smem, int buf, int r0, int n0, int k0, int w, int l)
{
  h16* dA = (h16*)(smem + buf * 16384);
  h16* dB = (h16*)(smem + 32768 + buf * 8192);
  // A: 256 rows x 32 k = 16 KB = 1024 x 16B chunks; 2 per thread
#pragma unroll
  for (int i = 0; i < 2; ++i) {
    const int ch = i * 512 + w * 64 + l;          // 0..1023
    const int row = ch >> 2;                      // 0..255 (4 chunks/row)
    const int kc = (ch & 3) ^ (row & 3);          // 16B-granule XOR swizzle
    gl_lds16(query + (size_t)(r0 + row) * EMB + k0 + kc * 8,
             dA + (size_t)(i * 512 + w * 64) * 8);
  }
  // B: 128 rows x 32 k = 8 KB = 512 x 16B chunks; 1 per thread
  {
    const int ch = w * 64 + l;                    // 0..511
    const int row = ch >> 2;                      // 0..127
    const int kc = (ch & 3) ^ (row & 3);
    int n = n0 + row; if (n > MEMN - 1) n = MEMN - 1;
    gl_lds16(memory + (size_t)n * EMB + k0 + kc * 8,
             dB + (size_t)(w * 64) * 8);
  }
}

__device__ __forceinline__ void sim_comp2(
    const char* smem, int buf, int wr, int wc, int l, f32x4 (&acc)[4][4])
{
  const h16* sA = (const h16*)(smem + buf * 16384);
  const h16* sB = (const h16*)(smem + 32768 + buf * 8192);
  half8 af[4], bfr[4];
#pragma unroll
  for (int mi = 0; mi < 4; ++mi) {
    const int row = wr * 64 + mi * 16 + (l & 15);       // 0..255
    const int slot = (l >> 4) ^ (row & 3);              // 0..3
    af[mi] = *(const half8*)&sA[row * 32 + slot * 8];
  }
#pragma unroll
  for (int ni = 0; ni < 4; ++ni) {
    const int row = wc * 64 + ni * 16 + (l & 15);       // 0..127
    const int slot = (l >> 4) ^ (row & 3);
    bfr[ni] = *(const half8*)&sB[row * 32 + slot * 8];
  }
  __builtin_amdgcn_s_setprio(1);
#pragma unroll
  for (int mi = 0; mi < 4; ++mi)
#pragma unroll
    for (int ni = 0; ni < 4; ++ni)
      acc[mi][ni] = __builtin_amdgcn_mfma_f32_16x16x32_f16(
          af[mi], bfr[ni], acc[mi][ni], 0, 0, 0);
  __builtin_amdgcn_s_setprio(0);
}

// =====================================================================
// K1a (fast path): sim = query @ memory^T, 256x128 tile, 8 waves, BK=32,
// double-buffered counted-vmcnt pipeline, 48 KB LDS -> 2 blocks/CU.
// grid (8 rowblocks, 64 chunks) = 512 blocks, all co-resident in one
// generation; XCD = rowblock%8 keeps the 512 KB A slice L2-resident;
// the two blocks on a CU share the A slice and stream different chunks.
// Emits per-chunk top-10 lists: cand[(c*10+j)][row]
// =====================================================================
__global__ void __launch_bounds__(512) k_sim_h(
    const h16* __restrict__ query, const h16* __restrict__ memory,
    float* __restrict__ cand_val, int* __restrict__ cand_idx)
{
  const int c  = blockIdx.y;             // chunk 0..63
  const int r0 = blockIdx.x * 256;       // row-block (XCD = blockIdx.x % 8)
  __shared__ __align__(16) char smem[49152];
  float* lS = (float*)smem;              // dump alias, 64 rows x stride 132

  const int t = threadIdx.x, w = t >> 6, l = t & 63;
  const int wr = w >> 1, wc = w & 1;     // 4M x 2N wave grid
  const int row_s = t >> 1, qq = t & 1;  // scan: row 0..255, col-half (64)

  float tv[TOPK]; int ti[TOPK];
#pragma unroll
  for (int j = 0; j < TOPK; ++j) { tv[j] = -3.0e38f; ti[j] = 0; }

  const int tile_beg = c * TPC;
  int tile_end = tile_beg + TPC; if (tile_end > NTILES) tile_end = NTILES;

  for (int tile = tile_beg; tile < tile_end; ++tile) {
    const int n0 = tile * 128;
    f32x4 acc[4][4] = {};

    // ---- pipelined K loop: 32 kt of BK=32, ping-pong, counted vmcnt ----
    sim_stage2(query, memory, smem, 0, r0, n0, 0, w, l);          // S0
#pragma unroll 1
    for (int kt = 0; kt < 30; kt += 2) {
      sim_stage2(query, memory, smem, 1, r0, n0, (kt + 1) * 32, w, l);
      bar_wait3();                       // waits S(kt); S(kt+1) in flight
      sim_comp2(smem, 0, wr, wc, l, acc);
      bar_sync();
      sim_stage2(query, memory, smem, 0, r0, n0, (kt + 2) * 32, w, l);
      bar_wait3();                       // waits S(kt+1)
      sim_comp2(smem, 1, wr, wc, l, acc);
      bar_sync();
    }
    sim_stage2(query, memory, smem, 1, r0, n0, 31 * 32, w, l);    // S31
    bar_wait3();                         // waits S30
    sim_comp2(smem, 0, wr, wc, l, acc);
    bar_sync();
    bar_wait0();                         // waits S31
    sim_comp2(smem, 1, wr, wc, l, acc);
    __syncthreads();                     // reads done before dump aliases

    // ---- dump + scan: 4 phases of 64 rows each (fits 48 KB alias) ----
#pragma unroll
    for (int p = 0; p < 4; ++p) {
      if (wr == p) {                     // waves 2p,2p+1 own rows p*64..+63
#pragma unroll
        for (int mi = 0; mi < 4; ++mi)
#pragma unroll
          for (int ni = 0; ni < 4; ++ni)
#pragma unroll
            for (int r = 0; r < 4; ++r) {
              const int rl = mi * 16 + (l >> 4) * 4 + r;      // 0..63
              const int col = wc * 64 + ni * 16 + (l & 15);   // 0..127
              lS[rl * 132 + col] = acc[mi][ni][r];
            }
      }
      __syncthreads();
      if ((row_s >> 6) == p) {
        const int rl = row_s & 63;
#pragma unroll
        for (int cc = 0; cc < 16; ++cc) {
          const int i4 = (cc + ((rl & 15))) & 15;             // bank stagger
          const int colb = qq * 64 + i4 * 4;
          const f32x4 v = *(const f32x4*)&lS[rl * 132 + colb];
          const float m = fmaxf(fmaxf(v[0], v[1]), fmaxf(v[2], v[3]));
          if (m > tv[TOPK - 1]) {
#pragma unroll
            for (int j = 0; j < 4; ++j) {
              const int g = n0 + colb + j;
              if (g < MEMN && v[j] > tv[TOPK - 1])
                topk_ins<TOPK>(tv, ti, v[j], g);
            }
          }
        }
      }
      __syncthreads();
    }
  }

  // ---- final merge: 2 col-half lists -> 1 list per (row, chunk) ----
  float* lSv = (float*)smem;
  int*   lSi = (int*)(smem + 20480);     // 256*20*4 = 20480 each -> 40 KB
#pragma unroll
  for (int j = 0; j < TOPK; ++j) {
    lSv[row_s * 20 + qq * TOPK + j] = tv[j];
    lSi[row_s * 20 + qq * TOPK + j] = ti[j];
  }
  __syncthreads();
  if (qq == 0) {
    float fv[TOPK]; int fi[TOPK];
#pragma unroll
    for (int j = 0; j < TOPK; ++j) { fv[j] = -3.0e38f; fi[j] = 0; }
    for (int m = 0; m < 20; ++m) {
      const float s = lSv[row_s * 20 + m];
      if (s > fv[TOPK - 1]) topk_ins<TOPK>(fv, fi, s, lSi[row_s * 20 + m]);
    }
    const int grow = r0 + row_s;
#pragma unroll
    for (int j = 0; j < TOPK; ++j) {
      cand_val[(size_t)(c * TOPK + j) * BATCH + grow] = fv[j];
      cand_idx[(size_t)(c * TOPK + j) * BATCH + grow] = fi[j];
    }
  }
}

// =====================================================================
// K1b (slow path, ws too small): 128x128 tile, stages FP32 tiles via
// global_load_lds and converts to fp16 during fragment reads. Legacy.
// =====================================================================
__global__ void __launch_bounds__(256) k_sim_f32(
    const float* __restrict__ query, const float* __restrict__ memory,
    float* __restrict__ cand_val, int* __restrict__ cand_idx)
{
  const int c  = blockIdx.x;
  const int r0 = blockIdx.y * 128;
  __shared__ __align__(16) char smem[65536];
  float* lA = (float*)smem;
  float* lB = (float*)(smem + 32768);
  float* lS = (float*)smem;

  const int t = threadIdx.x, w = t >> 6, l = t & 63;
  const int wr = w >> 1, wc = w & 1;
  const int row_s = t >> 2, qq = t & 3;

  float tvA[TOPK], tvB[TOPK]; int tiA[TOPK], tiB[TOPK];
#pragma unroll
  for (int j = 0; j < TOPK; ++j) { tvA[j] = -3.0e38f; tvB[j] = -3.0e38f; tiA[j] = 0; tiB[j] = 0; }

  const int tile_beg = c * TPC;
  int tile_end = tile_beg + TPC; if (tile_end > NTILES) tile_end = NTILES;

  for (int tile = tile_beg; tile < tile_end; ++tile) {
    const int n0 = tile * 128;
    f32x4 acc[4][4] = {};

    for (int kt = 0; kt < 16; ++kt) {
      const int k0 = kt * 64;
#pragma unroll
      for (int i = 0; i < 8; ++i) {
        const int c16 = (w * 8 + i) * 64 + l;
        const int row = c16 >> 4, s16 = c16 & 15;
        const int src = s16 ^ (row & 7);
        gl_lds16(query + (size_t)(r0 + row) * EMB + k0 + src * 4,
                 lA + (size_t)(w * 8 + i) * 256);
        int n = n0 + row; if (n > MEMN - 1) n = MEMN - 1;
        gl_lds16(memory + (size_t)n * EMB + k0 + src * 4,
                 lB + (size_t)(w * 8 + i) * 256);
      }
      __syncthreads();
#pragma unroll
      for (int ks = 0; ks < 2; ++ks) {
        half8 af[4], bfr[4];
#pragma unroll
        for (int mi = 0; mi < 4; ++mi) {
          const int row = wr * 64 + mi * 16 + (l & 15);
          const int g = ks * 4 + (l >> 4), m7 = row & 7;
          const f32x4 a0 = *(const f32x4*)(lA + row * 64 + (((2 * g)     ^ m7) << 2));
          const f32x4 a1 = *(const f32x4*)(lA + row * 64 + (((2 * g + 1) ^ m7) << 2));
          half8 f;
#pragma unroll
          for (int j = 0; j < 4; ++j) { f[j] = (h16)a0[j]; f[4 + j] = (h16)a1[j]; }
          af[mi] = f;
        }
#pragma unroll
        for (int ni = 0; ni < 4; ++ni) {
          const int row = wc * 64 + ni * 16 + (l & 15);
          const int g = ks * 4 + (l >> 4), m7 = row & 7;
          const f32x4 b0 = *(const f32x4*)(lB + row * 64 + (((2 * g)     ^ m7) << 2));
          const f32x4 b1 = *(const f32x4*)(lB + row * 64 + (((2 * g + 1) ^ m7) << 2));
          half8 f;
#pragma unroll
          for (int j = 0; j < 4; ++j) { f[j] = (h16)b0[j]; f[4 + j] = (h16)b1[j]; }
          bfr[ni] = f;
        }
#pragma unroll
        for (int mi = 0; mi < 4; ++mi)
#pragma unroll
          for (int ni = 0; ni < 4; ++ni)
            acc[mi][ni] = __builtin_amdgcn_mfma_f32_16x16x32_f16(
                af[mi], bfr[ni], acc[mi][ni], 0, 0, 0);
      }
      __syncthreads();
    }

#pragma unroll
    for (int ph = 0; ph < 2; ++ph) {
      if (wr == ph) {
#pragma unroll
        for (int mi = 0; mi < 4; ++mi)
#pragma unroll
          for (int ni = 0; ni < 4; ++ni)
#pragma unroll
            for (int r = 0; r < 4; ++r) {
              const int row_l = mi * 16 + (l >> 4) * 4 + r;
              const int col = wc * 64 + ni * 16 + (l & 15);
              lS[row_l * 131 + col] = acc[mi][ni][r];
            }
      }
      __syncthreads();
      float (&tv)[TOPK] = ph ? tvB : tvA; int (&ti)[TOPK] = ph ? tiB : tiA;
#pragma unroll 8
      for (int cc = 0; cc < 32; ++cc) {
        const int colt = qq * 32 + ((cc + qq * 8) & 31);
        const float s = lS[row_s * 131 + colt];
        const int g = n0 + colt;
        if (g < MEMN && s > tv[TOPK - 1]) topk_ins<TOPK>(tv, ti, s, g);
      }
      __syncthreads();
    }
  }

  float* lSv = (float*)smem;
  int*   lSi = (int*)(smem + 10240);
#pragma unroll
  for (int ph = 0; ph < 2; ++ph) {
#pragma unroll
    for (int j = 0; j < TOPK; ++j) {
      lSv[row_s * 40 + qq * TOPK + j] = ph ? tvB[j] : tvA[j];
      lSi[row_s * 40 + qq * TOPK + j] = ph ? tiB[j] : tiA[j];
    }
    __syncthreads();
    if (qq == 0) {
      float fv[TOPK]; int fi[TOPK];
#pragma unroll
      for (int j = 0; j < TOPK; ++j) { fv[j] = -3.0e38f; fi[j] = 0; }
      for (int m = 0; m < 40; ++m) {
        const float s = lSv[row_s * 40 + m];
        if (s > fv[TOPK - 1]) topk_ins<TOPK>(fv, fi, s, lSi[row_s * 40 + m]);
      }
      const int grow = r0 + ph * 64 + row_s;
#pragma unroll
      for (int j = 0; j < TOPK; ++j) {
        cand_val[(size_t)(c * TOPK + j) * BATCH + grow] = fv[j];
        cand_idx[(size_t)(c * TOPK + j) * BATCH + grow] = fi[j];
      }
    }
    __syncthreads();
  }
}

// =====================================================================
// K2: merge nch chunk lists -> coarse top-20 indices
// =====================================================================
__global__ void __launch_bounds__(256) k_merge20(
    const float* __restrict__ cand_val, const int* __restrict__ cand_idx,
    int* __restrict__ idx20, int nch)
{
  const int row = blockIdx.x * 256 + threadIdx.x;
  float tv[CAND]; int ti[CAND];
#pragma unroll
  for (int j = 0; j < CAND; ++j) { tv[j] = -3.0e38f; ti[j] = 0; }
  for (int m = 0; m < nch * TOPK; ++m) {
    const float s = cand_val[(size_t)m * BATCH + row];
    if (s > tv[CAND - 1]) {
      const int gi = cand_idx[(size_t)m * BATCH + row];
      topk_ins<CAND>(tv, ti, s, gi);
    }
  }
#pragma unroll
  for (int j = 0; j < CAND; ++j) idx20[row * CAND + j] = ti[j];
}

// =====================================================================
// K3: exact fp64 rescore of 20 candidates -> final top-10 set.
// One wave per batch row.
// =====================================================================
__global__ void __launch_bounds__(256) k_rescore(
    const float* __restrict__ query, const float* __restrict__ memory,
    const int* __restrict__ idx20, int* __restrict__ idx10)
{
  const int w = threadIdx.x >> 6, l = threadIdx.x & 63;
  const int b = blockIdx.x * 4 + w;
  const float* qp = query + (size_t)b * EMB + l * 16;
  float q[16];
#pragma unroll
  for (int j = 0; j < 4; ++j) {
    const f32x4 v = *(const f32x4*)(qp + 4 * j);
#pragma unroll
    for (int i = 0; i < 4; ++i) q[j * 4 + i] = v[i];
  }
  double sc[CAND];
#pragma unroll
  for (int cc = 0; cc < CAND; ++cc) {
    const int mi = idx20[b * CAND + cc];
    const float* mp = memory + (size_t)mi * EMB + l * 16;
    double s = 0.0;
#pragma unroll
    for (int j = 0; j < 4; ++j) {
      const f32x4 v = *(const f32x4*)(mp + 4 * j);
#pragma unroll
      for (int i = 0; i < 4; ++i) s += (double)q[j * 4 + i] * (double)v[i];
    }
#pragma unroll
    for (int o = 1; o < 64; o <<= 1) s += __shfl_xor(s, o);
    sc[cc] = s;
  }
  if (l == 0) {
    unsigned used = 0;
#pragma unroll
    for (int j = 0; j < TOPK; ++j) {
      double best = -1.0e300; int bi = 0;
#pragma unroll
      for (int cc = 0; cc < CAND; ++cc)
        if (!((used >> cc) & 1u) && sc[cc] > best) { best = sc[cc]; bi = cc; }
      used |= 1u << bi;
      idx10[b * TOPK + j] = idx20[b * CAND + bi];
    }
  }
}

// =====================================================================
// K4: fp16 BT-GEMM, head-batched via blockIdx.z.
// C[m][ccol+n] = sum_k A[m*astr+acol+k]*Bt[n*1024+bcol+k] (+ bias[n]);
// out to fp16 (outH) or fp32 (outF). Per-z offsets: acol+=z*aoffz,
// bcol+=z*boffz, ccol+=z*coffz, bias+=z*biasoffz.
// grid (N/128, M/128, Z), 256 threads, BK=64.
// =====================================================================
__global__ void __launch_bounds__(256) k_gemm16(
    const h16* __restrict__ A, int astr, int acol, int aoffz,
    const h16* __restrict__ Bt, int bcol, int boffz,
    const float* __restrict__ bias, int biasoffz,
    h16* __restrict__ outH, float* __restrict__ outF,
    int cstr, int ccol, int coffz, int nkt)
{
  const int z = blockIdx.z;
  acol += z * aoffz; bcol += z * boffz; ccol += z * coffz;
  const float* bp = bias ? bias + z * biasoffz : nullptr;

  const int c0 = blockIdx.x * 128, r0 = blockIdx.y * 128;
  __shared__ __align__(16) h16 lA[128 * 64], lB[128 * 64];
  const int t = threadIdx.x, w = t >> 6, l = t & 63;
  const int wr = w >> 1, wc = w & 1;
  f32x4 acc[4][4] = {};

  for (int kt = 0; kt < nkt; ++kt) {
    const int k0 = kt * 64;
#pragma unroll
    for (int i = 0; i < 4; ++i) {
      const int ch = w * 256 + i * 64 + l;
      const int row = ch >> 3;
      const int kc = (ch & 7) ^ (row & 7);
      gl_lds16(A  + (size_t)(r0 + row) * astr + acol + k0 + kc * 8,
               lA + (size_t)(w * 256 + i * 64) * 8);
      gl_lds16(Bt + (size_t)(c0 + row) * EMB + bcol + k0 + kc * 8,
               lB + (size_t)(w * 256 + i * 64) * 8);
    }
    __syncthreads();
#pragma unroll
    for (int ks = 0; ks < 2; ++ks) {
      half8 af[4], bfr[4];
#pragma unroll
      for (int mi = 0; mi < 4; ++mi) {
        const int row = wr * 64 + mi * 16 + (l & 15);
        const int slot = (ks * 4 + (l >> 4)) ^ (row & 7);
        af[mi] = *(const half8*)&lA[row * 64 + slot * 8];
      }
#pragma unroll
      for (int ni = 0; ni < 4; ++ni) {
        const int row = wc * 64 + ni * 16 + (l & 15);
        const int slot = (ks * 4 + (l >> 4)) ^ (row & 7);
        bfr[ni] = *(const half8*)&lB[row * 64 + slot * 8];
      }
#pragma unroll
      for (int mi = 0; mi < 4; ++mi)
#pragma unroll
        for (int ni = 0; ni < 4; ++ni)
          acc[mi][ni] = __builtin_amdgcn_mfma_f32_16x16x32_f16(
              af[mi], bfr[ni], acc[mi][ni], 0, 0, 0);
    }
    __syncthreads();
  }
#pragma unroll
  for (int ni = 0; ni < 4; ++ni) {
    const int ncol = c0 + wc * 64 + ni * 16 + (l & 15);
    const float bv = bp ? bp[ncol] : 0.0f;
#pragma unroll
    for (int mi = 0; mi < 4; ++mi)
#pragma unroll
      for (int r = 0; r < 4; ++r) {
        const int grow = r0 + wr * 64 + mi * 16 + (l >> 4) * 4 + r;
        const float v = acc[mi][ni][r] + bv;
        if (outH) outH[(size_t)grow * cstr + ccol + ncol] = (h16)v;
        else      outF[(size_t)grow * cstr + ccol + ncol] = v;
      }
  }
}

// =====================================================================
// K5: attention over all 8 heads, ONLINE softmax (single pass over the
// 10 rows per head). One wave per batch row.
// qtA[b][h*1024+:] holds qt on entry; overwritten with mv per head.
// =====================================================================
__global__ void __launch_bounds__(256) k_attn(
    const float* __restrict__ memory, const int* __restrict__ idx10,
    h16* __restrict__ qtA)
{
  const int w = threadIdx.x >> 6, l = threadIdx.x & 63;
  const int b = blockIdx.x * 4 + w;
  int rows[TOPK];
#pragma unroll
  for (int k = 0; k < TOPK; ++k) rows[k] = idx10[b * TOPK + k];

  for (int h = 0; h < HEADS; ++h) {
    h16* qp = qtA + (size_t)b * (HEADS * EMB) + h * EMB + l * 16;
    const half8 qa = *(const half8*)qp;
    const half8 qb = *(const half8*)(qp + 8);
    float qf[16];
#pragma unroll
    for (int j = 0; j < 8; ++j) { qf[j] = (float)qa[j]; qf[8 + j] = (float)qb[j]; }

    float mrun = -3.0e38f, den = 0.f;
    float acc[16];
#pragma unroll
    for (int j = 0; j < 16; ++j) acc[j] = 0.f;

#pragma unroll
    for (int k = 0; k < TOPK; ++k) {
      const float* mp = memory + (size_t)rows[k] * EMB + l * 16;
      float mv[16]; float p = 0.f;
#pragma unroll
      for (int j = 0; j < 4; ++j) {
        const f32x4 m = *(const f32x4*)(mp + 4 * j);
#pragma unroll
        for (int i = 0; i < 4; ++i) { mv[j * 4 + i] = m[i]; p += qf[j * 4 + i] * m[i]; }
      }
#pragma unroll
      for (int o = 1; o < 64; o <<= 1) p += __shfl_xor(p, o);
      p *= SCALE;
      if (p > mrun) {                    // wave-uniform
        const float rs = __expf(mrun - p);   // first iter: exp(-huge)=0
        den *= rs;
#pragma unroll
        for (int j = 0; j < 16; ++j) acc[j] *= rs;
        mrun = p;
      }
      const float e = __expf(p - mrun);
      den += e;
#pragma unroll
      for (int j = 0; j < 16; ++j) acc[j] += e * mv[j];
    }
    const float inv = 1.0f / den;
    half8 o0, o1;
#pragma unroll
    for (int j = 0; j < 8; ++j) {
      o0[j] = (h16)(acc[j] * inv);
      o1[j] = (h16)(acc[8 + j] * inv);
    }
    *(half8*)qp = o0;
    *(half8*)(qp + 8) = o1;
  }
}

// =====================================================================
extern "C" void kernel_launch(void* const* d_in, const int* in_sizes, int n_in,
                              void* d_out, int out_size, void* d_ws, size_t ws_size,
                              hipStream_t stream)
{
  const float* query  = (const float*)d_in[0];
  const float* memory = (const float*)d_in[1];
  const float* w_q    = (const float*)d_in[2];
  const float* w_k    = (const float*)d_in[3];
  const float* w_v    = (const float*)d_in[4];
  const float* b_q    = (const float*)d_in[5];
  // b_k (d_in[6]) cancels in softmax
  const float* b_v    = (const float*)d_in[7];
  const float* w_o    = (const float*)d_in[8];
  const float* b_o    = (const float*)d_in[9];

  char* ws = (char*)d_ws;
  float* cand_val = (float*)(ws + 0);            //  5,242,880
  int*   cand_idx = (int*)  (ws + 5242880);      //  5,242,880
  int*   idx20    = (int*)  (ws + 10485760);     //    163,840
  int*   idx10    = (int*)  (ws + 10649600);     //     81,920
  h16*   qH       = (h16*)  (ws + 10731520);     //  4,194,304
  h16*   wqH      = (h16*)  (ws + 14925824);     //  2,097,152
  h16*   wkTH     = (h16*)  (ws + 17022976);     //  2,097,152
  h16*   wvH      = (h16*)  (ws + 19120128);     //  2,097,152
  h16*   woH      = (h16*)  (ws + 21217280);     //  2,097,152
  h16*   qpH      = (h16*)  (ws + 23314432);     //  4,194,304
  h16*   qtA      = (h16*)  (ws + 27508736);     // 33,554,432 (qt then mv)
  h16*   ctxH     = (h16*)  (ws + 61063168);     //  4,194,304  -> end 65,257,472
  h16*   memH     = (h16*)  (ws + 65257472);     // 204,800,000 -> end 270,057,472

  const bool fast = ws_size >= 270057472ULL;     // constant per deployment

  // conversions
  if (fast) k_f2h<<<8192, 256, 0, stream>>>(memory, memH, 25600000L);
  k_f2h <<<2048, 256, 0, stream>>>(query, qH, 524288L);
  k_f2h3<<<dim3(1024, 3), 256, 0, stream>>>(w_q, w_v, w_o, wqH, wvH, woH);
  k_f2hT<<<dim3(16, 16), 256, 0, stream>>>(w_k, wkTH);

  // retrieval: coarse fp16 scores + per-chunk top-10
  if (fast) k_sim_h  <<<dim3(8, CHUNKS), 512, 0, stream>>>(qH, memH, cand_val, cand_idx);
  else      k_sim_f32<<<dim3(CHUNKS, 16), 256, 0, stream>>>(query, memory, cand_val, cand_idx);
  // coarse top-20, then exact fp64 rescore -> final top-10 set
  k_merge20<<<BATCH / 256, 256, 0, stream>>>(cand_val, cand_idx, idx20, CHUNKS);
  k_rescore<<<BATCH / 4, 256, 0, stream>>>(query, memory, idx20, idx10);

  // q projection: qpH = query @ w_q^T + b_q
  k_gemm16<<<dim3(8, 16), 256, 0, stream>>>(qH, EMB, 0, 0, wqH, 0, 0,
                                            b_q, 0, qpH, nullptr, EMB, 0, 0, 16);
  // per-head qt (all 8 heads in one launch):
  // qtA[b][h*1024+e] = sum_d qpH[b][h*128+d] * w_k[h*128+d][e]
  k_gemm16<<<dim3(8, 16, 8), 256, 0, stream>>>(qpH, EMB, 0, HDIM, wkTH, 0, HDIM,
                                               nullptr, 0, qtA, nullptr,
                                               HEADS * EMB, 0, EMB, 2);
  // attention (scores vs fp32 memory, online softmax, mv in place)
  k_attn<<<BATCH / 4, 256, 0, stream>>>(memory, idx10, qtA);
  // per-head ctx (all 8 heads in one launch):
  // ctxH[b][h*128+d] = sum_e mv[b][h*1024+e]*w_v[h*128+d][e] + b_v
  k_gemm16<<<dim3(1, 16, 8), 256, 0, stream>>>(qtA, HEADS * EMB, 0, EMB,
                                               wvH, 0, HDIM * EMB,
                                               b_v, HDIM, ctxH, nullptr,
                                               EMB, 0, HDIM, 16);
  // output projection -> fp32 d_out
  k_gemm16<<<dim3(8, 16), 256, 0, stream>>>(ctxH, EMB, 0, 0, woH, 0, 0,
                                            b_o, 0, nullptr, (float*)d_out,
                                            EMB, 0, 0, 16);
}

// Round 10
// 2161.041 us; speedup vs baseline: 2.3488x; 2.3488x over previous
//
#include <hip/hip_runtime.h>
#include <cstdint>
#include <cstddef>

// Problem constants (inputs are FLOAT32; output float32)
#define BATCH   2048
#define EMB     1024
#define HEADS   8
#define HDIM    128
#define TOPK    10
#define MEMN    100000
#define NTILES  782          // ceil(100000/128)  (BN=128 col tiles)
#define CHUNKS  64
#define TPC     13           // 64*13 = 832 >= 782
#define CAND    20           // rescored candidate count
#define SCALE   0.08838834764831845f

// TOOLCHAIN/HW LAWS (measured R1-R9):
// 1) hipcc allocates ~1024/(waves-per-block) VGPRs regardless of
//    __launch_bounds__ 2nd arg: 4w->~256, 8w->~128, 16w->64. Exceeding it
//    spills acc to scratch (WRITE_SIZE 10MB -> 1.4-17GB).
// 2) Fragment-read bank spread needs the full 8-slot XOR (BK=64, 128B row
//    stride). BK=32's 4-slot swizzle = 4-way conflicts (R9: 54.7M, 13x).
// 3) Co-residency >1 block/CU never materializes here (occupancy == one
//    block in every round). Only per-block amortization moves sim.
// => sim frozen at R4 shape: 256x128, 8 waves, BK=64, dbuf, counted vmcnt.

typedef _Float16 h16;
typedef _Float16 half8 __attribute__((ext_vector_type(8)));
typedef _Float16 half4 __attribute__((ext_vector_type(4)));
typedef float    f32x4 __attribute__((ext_vector_type(4)));

// ---- async global->LDS, 16B per lane (wave-uniform LDS base + lane*16) ----
__device__ __forceinline__ void gl_lds16(const void* g, void* l) {
  __builtin_amdgcn_global_load_lds(
      (const __attribute__((address_space(1))) unsigned int*)g,
      (__attribute__((address_space(3))) unsigned int*)l, 16, 0, 0);
}

// ---- pipeline barriers (counted vmcnt: loads stay in flight across bar) ----
__device__ __forceinline__ void bar_sync() {   // barrier, NO vm drain
  asm volatile("" ::: "memory");
  __builtin_amdgcn_s_barrier();
  __builtin_amdgcn_sched_barrier(0);
}
__device__ __forceinline__ void bar_wait6() {  // wait all but newest 6 loads
  asm volatile("s_waitcnt vmcnt(6)" ::: "memory");
  __builtin_amdgcn_s_barrier();
  __builtin_amdgcn_sched_barrier(0);
}
__device__ __forceinline__ void bar_wait0() {  // full vm drain + barrier
  asm volatile("s_waitcnt vmcnt(0)" ::: "memory");
  __builtin_amdgcn_s_barrier();
  __builtin_amdgcn_sched_barrier(0);
}

// ---- register top-N insertion ----
template <int N>
__device__ __forceinline__ void topk_ins(float (&tv)[N], int (&ti)[N],
                                         float s, int gi) {
  float cv = s; int ci = gi;
#pragma unroll
  for (int j = 0; j < N; ++j) {
    bool sw = tv[j] < cv;
    float tf = tv[j]; int tt = ti[j];
    if (sw) { tv[j] = cv; ti[j] = ci; cv = tf; ci = tt; }
  }
}

// =====================================================================
// Conversion kernels
// =====================================================================
// memory f32 -> fp16: 32B in / 16B out per iteration (half8 stores)
__global__ void __launch_bounds__(256) k_f2hW(
    const float* __restrict__ in, h16* __restrict__ out, long n8)
{
  long i = (long)blockIdx.x * 256 + threadIdx.x;
  const long stride = (long)gridDim.x * 256;
  for (; i < n8; i += stride) {
    const f32x4 a = ((const f32x4*)in)[2 * i];
    const f32x4 b = ((const f32x4*)in)[2 * i + 1];
    half8 o;
#pragma unroll
    for (int j = 0; j < 4; ++j) { o[j] = (h16)a[j]; o[4 + j] = (h16)b[j]; }
    ((half8*)out)[i] = o;
  }
}

// query + w_q + w_v + w_o conversions in ONE launch (flat index, segment
// select). 524288 + 3*262144 = 1,310,720 f32x4 -> grid 5120 x 256 exact.
__global__ void __launch_bounds__(256) k_convA(
    const float* __restrict__ q,  const float* __restrict__ wq,
    const float* __restrict__ wv, const float* __restrict__ wo,
    h16* __restrict__ qH, h16* __restrict__ wqH,
    h16* __restrict__ wvH, h16* __restrict__ woH)
{
  const long i = (long)blockIdx.x * 256 + threadIdx.x;
  const float* in; h16* out; long off;
  if (i < 524288)        { in = q;  out = qH;  off = i; }
  else if (i < 786432)   { in = wq; out = wqH; off = i - 524288; }
  else if (i < 1048576)  { in = wv; out = wvH; off = i - 786432; }
  else                   { in = wo; out = woH; off = i - 1048576; }
  const f32x4 v = ((const f32x4*)in)[off];
  half4 o;
#pragma unroll
  for (int j = 0; j < 4; ++j) o[j] = (h16)v[j];
  ((half4*)out)[off] = o;
}

// w_k [n][e] -> wkT fp16 [e][n], tiled via LDS (both sides coalesced)
__global__ void __launch_bounds__(256) k_f2hT(
    const float* __restrict__ in, h16* __restrict__ out)
{
  __shared__ float tl[64][65];
  const int n0 = blockIdx.x * 64, e0 = blockIdx.y * 64;
  const int cc = threadIdx.x & 63, rb = threadIdx.x >> 6;
#pragma unroll
  for (int i = 0; i < 16; ++i) {
    const int r = i * 4 + rb;
    tl[r][cc] = in[(size_t)(n0 + r) * EMB + e0 + cc];
  }
  __syncthreads();
#pragma unroll
  for (int i = 0; i < 16; ++i) {
    const int r = i * 4 + rb;        // e-local
    out[(size_t)(e0 + r) * EMB + n0 + cc] = (h16)tl[cc][r];
  }
}

// =====================================================================
// K1a helpers (fast path): BM=256 x BN=128 tile, 8 waves (4M x 2N),
// per-wave output 64x64 (acc = 64 VGPR, spill-safe).  [R4-exact]
// LDS (96 KB): A0 [0,32K) A1 [32K,64K) B0 [64K,80K) B1 [80K,96K)
// =====================================================================
__device__ __forceinline__ void sim_stage2(
    const h16* __restrict__ query, const h16* __restrict__ memory,
    char* smem, int buf, int r0, int n0, int k0, int w, int l)
{
  h16* dA = (h16*)(smem + buf * 32768);
  h16* dB = (h16*)(smem + 65536 + buf * 16384);
  // A: 256 rows x 64 k = 32 KB = 2048 x 16B chunks; 4 per thread
#pragma unroll
  for (int i = 0; i < 4; ++i) {
    const int ch = i * 512 + w * 64 + l;          // 0..2047
    const int row = ch >> 3;                      // 0..255
    const int kc = (ch & 7) ^ (row & 7);          // 16B-granule XOR swizzle
    gl_lds16(query + (size_t)(r0 + row) * EMB + k0 + kc * 8,
             dA + (size_t)(i * 512 + w * 64) * 8);
  }
  // B: 128 rows x 64 k = 16 KB = 1024 x 16B chunks; 2 per thread
#pragma unroll
  for (int i = 0; i < 2; ++i) {
    const int ch = i * 512 + w * 64 + l;          // 0..1023
    const int row = ch >> 3;                      // 0..127
    const int kc = (ch & 7) ^ (row & 7);
    int n = n0 + row; if (n > MEMN - 1) n = MEMN - 1;
    gl_lds16(memory + (size_t)n * EMB + k0 + kc * 8,
             dB + (size_t)(i * 512 + w * 64) * 8);
  }
}

__device__ __forceinline__ void sim_comp2(
    const char* smem, int buf, int wr, int wc, int l, f32x4 (&acc)[4][4])
{
  const h16* sA = (const h16*)(smem + buf * 32768);
  const h16* sB = (const h16*)(smem + 65536 + buf * 16384);
#pragma unroll
  for (int ks = 0; ks < 2; ++ks) {
    half8 af[4], bfr[4];
#pragma unroll
    for (int mi = 0; mi < 4; ++mi) {
      const int row = wr * 64 + mi * 16 + (l & 15);       // 0..255
      const int slot = (ks * 4 + (l >> 4)) ^ (row & 7);
      af[mi] = *(const half8*)&sA[row * 64 + slot * 8];
    }
#pragma unroll
    for (int ni = 0; ni < 4; ++ni) {
      const int row = wc * 64 + ni * 16 + (l & 15);       // 0..127
      const int slot = (ks * 4 + (l >> 4)) ^ (row & 7);
      bfr[ni] = *(const half8*)&sB[row * 64 + slot * 8];
    }
    __builtin_amdgcn_s_setprio(1);
#pragma unroll
    for (int mi = 0; mi < 4; ++mi)
#pragma unroll
      for (int ni = 0; ni < 4; ++ni)
        acc[mi][ni] = __builtin_amdgcn_mfma_f32_16x16x32_f16(
            af[mi], bfr[ni], acc[mi][ni], 0, 0, 0);
    __builtin_amdgcn_s_setprio(0);
  }
}

// =====================================================================
// K1a (fast path): sim = query @ memory^T, 256x128 tile, 8 waves, BK=64,
// double-buffered counted-vmcnt pipeline. [R4-exact: 997us, 120 VGPR]
// grid (8 rowblocks, 64 chunks); XCD = rowblock%8 keeps the 512 KB A
// slice L2-resident.
// Emits per-chunk top-10 lists: cand[(c*10+j)][row]
// =====================================================================
__global__ void __launch_bounds__(512) k_sim_h(
    const h16* __restrict__ query, const h16* __restrict__ memory,
    float* __restrict__ cand_val, int* __restrict__ cand_idx)
{
  const int c  = blockIdx.y;             // chunk 0..63
  const int r0 = blockIdx.x * 256;       // row-block (XCD = blockIdx.x % 8)
  __shared__ __align__(16) char smem[98304];
  float* lS = (float*)smem;              // dump alias, 128 rows x stride 132

  const int t = threadIdx.x, w = t >> 6, l = t & 63;
  const int wr = w >> 1, wc = w & 1;     // 4M x 2N wave grid
  const int row_s = t >> 2, qq = t & 3;  // scan: row 0..127, col-quarter

  float tvA[TOPK], tvB[TOPK]; int tiA[TOPK], tiB[TOPK];
#pragma unroll
  for (int j = 0; j < TOPK; ++j) { tvA[j] = -3.0e38f; tvB[j] = -3.0e38f; tiA[j] = 0; tiB[j] = 0; }

  const int tile_beg = c * TPC;
  int tile_end = tile_beg + TPC; if (tile_end > NTILES) tile_end = NTILES;

  for (int tile = tile_beg; tile < tile_end; ++tile) {
    const int n0 = tile * 128;
    f32x4 acc[4][4] = {};

    // ---- pipelined K loop: 16 kt of BK=64, ping-pong, counted vmcnt ----
    sim_stage2(query, memory, smem, 0, r0, n0, 0, w, l);          // S0
#pragma unroll 1
    for (int kt = 0; kt < 14; kt += 2) {
      sim_stage2(query, memory, smem, 1, r0, n0, (kt + 1) * 64, w, l);
      bar_wait6();                       // waits S(kt); S(kt+1) in flight
      sim_comp2(smem, 0, wr, wc, l, acc);
      bar_sync();
      sim_stage2(query, memory, smem, 0, r0, n0, (kt + 2) * 64, w, l);
      bar_wait6();                       // waits S(kt+1)
      sim_comp2(smem, 1, wr, wc, l, acc);
      bar_sync();
    }
    sim_stage2(query, memory, smem, 1, r0, n0, 15 * 64, w, l);    // S15
    bar_wait6();                         // waits S14
    sim_comp2(smem, 0, wr, wc, l, acc);
    bar_sync();
    bar_wait0();                         // waits S15
    sim_comp2(smem, 1, wr, wc, l, acc);
    __syncthreads();                     // reads done before dump aliases

    // ---- dump + scan: 2 phases of 128 rows each ----
#pragma unroll
    for (int ph = 0; ph < 2; ++ph) {
      if ((wr >> 1) == ph) {             // waves owning rows ph*128..+127
#pragma unroll
        for (int mi = 0; mi < 4; ++mi)
#pragma unroll
          for (int ni = 0; ni < 4; ++ni)
#pragma unroll
            for (int r = 0; r < 4; ++r) {
              const int row_l = (wr & 1) * 64 + mi * 16 + (l >> 4) * 4 + r;
              const int col = wc * 64 + ni * 16 + (l & 15);
              lS[row_l * 132 + col] = acc[mi][ni][r];
            }
      }
      __syncthreads();
      float (&tv)[TOPK] = ph ? tvB : tvA; int (&ti)[TOPK] = ph ? tiB : tiA;
#pragma unroll
      for (int cc = 0; cc < 8; ++cc) {
        const int c4 = qq * 32 + ((cc + qq * 2) & 7) * 4;   // bank stagger
        const f32x4 v = *(const f32x4*)&lS[row_s * 132 + c4];
        const float m = fmaxf(fmaxf(v[0], v[1]), fmaxf(v[2], v[3]));
        if (m > tv[TOPK - 1]) {
#pragma unroll
          for (int j = 0; j < 4; ++j) {
            const int g = n0 + c4 + j;
            if (g < MEMN && v[j] > tv[TOPK - 1]) topk_ins<TOPK>(tv, ti, v[j], g);
          }
        }
      }
      __syncthreads();
    }
  }

  // quarter-merge: 4 quarter-lists -> 1 list per (row, chunk)
  float* lSv = (float*)smem;
  int*   lSi = (int*)(smem + 20480);     // 128*40*4 = 20480 each
#pragma unroll
  for (int ph = 0; ph < 2; ++ph) {
#pragma unroll
    for (int j = 0; j < TOPK; ++j) {
      lSv[row_s * 40 + qq * TOPK + j] = ph ? tvB[j] : tvA[j];
      lSi[row_s * 40 + qq * TOPK + j] = ph ? tiB[j] : tiA[j];
    }
    __syncthreads();
    if (qq == 0) {
      float fv[TOPK]; int fi[TOPK];
#pragma unroll
      for (int j = 0; j < TOPK; ++j) { fv[j] = -3.0e38f; fi[j] = 0; }
      for (int m = 0; m < 40; ++m) {
        const float s = lSv[row_s * 40 + m];
        if (s > fv[TOPK - 1]) topk_ins<TOPK>(fv, fi, s, lSi[row_s * 40 + m]);
      }
      const int grow = r0 + ph * 128 + row_s;
#pragma unroll
      for (int j = 0; j < TOPK; ++j) {
        cand_val[(size_t)(c * TOPK + j) * BATCH + grow] = fv[j];
        cand_idx[(size_t)(c * TOPK + j) * BATCH + grow] = fi[j];
      }
    }
    __syncthreads();
  }
}

// =====================================================================
// K1b (slow path, ws too small): 128x128 tile, stages FP32 tiles via
// global_load_lds and converts to fp16 during fragment reads. Legacy.
// =====================================================================
__global__ void __launch_bounds__(256) k_sim_f32(
    const float* __restrict__ query, const float* __restrict__ memory,
    float* __restrict__ cand_val, int* __restrict__ cand_idx)
{
  const int c  = blockIdx.x;
  const int r0 = blockIdx.y * 128;
  __shared__ __align__(16) char smem[65536];
  float* lA = (float*)smem;
  float* lB = (float*)(smem + 32768);
  float* lS = (float*)smem;

  const int t = threadIdx.x, w = t >> 6, l = t & 63;
  const int wr = w >> 1, wc = w & 1;
  const int row_s = t >> 2, qq = t & 3;

  float tvA[TOPK], tvB[TOPK]; int tiA[TOPK], tiB[TOPK];
#pragma unroll
  for (int j = 0; j < TOPK; ++j) { tvA[j] = -3.0e38f; tvB[j] = -3.0e38f; tiA[j] = 0; tiB[j] = 0; }

  const int tile_beg = c * TPC;
  int tile_end = tile_beg + TPC; if (tile_end > NTILES) tile_end = NTILES;

  for (int tile = tile_beg; tile < tile_end; ++tile) {
    const int n0 = tile * 128;
    f32x4 acc[4][4] = {};

    for (int kt = 0; kt < 16; ++kt) {
      const int k0 = kt * 64;
#pragma unroll
      for (int i = 0; i < 8; ++i) {
        const int c16 = (w * 8 + i) * 64 + l;
        const int row = c16 >> 4, s16 = c16 & 15;
        const int src = s16 ^ (row & 7);
        gl_lds16(query + (size_t)(r0 + row) * EMB + k0 + src * 4,
                 lA + (size_t)(w * 8 + i) * 256);
        int n = n0 + row; if (n > MEMN - 1) n = MEMN - 1;
        gl_lds16(memory + (size_t)n * EMB + k0 + src * 4,
                 lB + (size_t)(w * 8 + i) * 256);
      }
      __syncthreads();
#pragma unroll
      for (int ks = 0; ks < 2; ++ks) {
        half8 af[4], bfr[4];
#pragma unroll
        for (int mi = 0; mi < 4; ++mi) {
          const int row = wr * 64 + mi * 16 + (l & 15);
          const int g = ks * 4 + (l >> 4), m7 = row & 7;
          const f32x4 a0 = *(const f32x4*)(lA + row * 64 + (((2 * g)     ^ m7) << 2));
          const f32x4 a1 = *(const f32x4*)(lA + row * 64 + (((2 * g + 1) ^ m7) << 2));
          half8 f;
#pragma unroll
          for (int j = 0; j < 4; ++j) { f[j] = (h16)a0[j]; f[4 + j] = (h16)a1[j]; }
          af[mi] = f;
        }
#pragma unroll
        for (int ni = 0; ni < 4; ++ni) {
          const int row = wc * 64 + ni * 16 + (l & 15);
          const int g = ks * 4 + (l >> 4), m7 = row & 7;
          const f32x4 b0 = *(const f32x4*)(lB + row * 64 + (((2 * g)     ^ m7) << 2));
          const f32x4 b1 = *(const f32x4*)(lB + row * 64 + (((2 * g + 1) ^ m7) << 2));
          half8 f;
#pragma unroll
          for (int j = 0; j < 4; ++j) { f[j] = (h16)b0[j]; f[4 + j] = (h16)b1[j]; }
          bfr[ni] = f;
        }
#pragma unroll
        for (int mi = 0; mi < 4; ++mi)
#pragma unroll
          for (int ni = 0; ni < 4; ++ni)
            acc[mi][ni] = __builtin_amdgcn_mfma_f32_16x16x32_f16(
                af[mi], bfr[ni], acc[mi][ni], 0, 0, 0);
      }
      __syncthreads();
    }

#pragma unroll
    for (int ph = 0; ph < 2; ++ph) {
      if (wr == ph) {
#pragma unroll
        for (int mi = 0; mi < 4; ++mi)
#pragma unroll
          for (int ni = 0; ni < 4; ++ni)
#pragma unroll
            for (int r = 0; r < 4; ++r) {
              const int row_l = mi * 16 + (l >> 4) * 4 + r;
              const int col = wc * 64 + ni * 16 + (l & 15);
              lS[row_l * 131 + col] = acc[mi][ni][r];
            }
      }
      __syncthreads();
      float (&tv)[TOPK] = ph ? tvB : tvA; int (&ti)[TOPK] = ph ? tiB : tiA;
#pragma unroll 8
      for (int cc = 0; cc < 32; ++cc) {
        const int colt = qq * 32 + ((cc + qq * 8) & 31);
        const float s = lS[row_s * 131 + colt];
        const int g = n0 + colt;
        if (g < MEMN && s > tv[TOPK - 1]) topk_ins<TOPK>(tv, ti, s, g);
      }
      __syncthreads();
    }
  }

  float* lSv = (float*)smem;
  int*   lSi = (int*)(smem + 10240);
#pragma unroll
  for (int ph = 0; ph < 2; ++ph) {
#pragma unroll
    for (int j = 0; j < TOPK; ++j) {
      lSv[row_s * 40 + qq * TOPK + j] = ph ? tvB[j] : tvA[j];
      lSi[row_s * 40 + qq * TOPK + j] = ph ? tiB[j] : tiA[j];
    }
    __syncthreads();
    if (qq == 0) {
      float fv[TOPK]; int fi[TOPK];
#pragma unroll
      for (int j = 0; j < TOPK; ++j) { fv[j] = -3.0e38f; fi[j] = 0; }
      for (int m = 0; m < 40; ++m) {
        const float s = lSv[row_s * 40 + m];
        if (s > fv[TOPK - 1]) topk_ins<TOPK>(fv, fi, s, lSi[row_s * 40 + m]);
      }
      const int grow = r0 + ph * 64 + row_s;
#pragma unroll
      for (int j = 0; j < TOPK; ++j) {
        cand_val[(size_t)(c * TOPK + j) * BATCH + grow] = fv[j];
        cand_idx[(size_t)(c * TOPK + j) * BATCH + grow] = fi[j];
      }
    }
    __syncthreads();
  }
}

// =====================================================================
// K2: merge 64 chunk lists -> coarse top-20 indices.
// 32 blocks x 256 threads: thread = (row-local rl = t>>2, quarter qq=t&3);
// each thread scans 160 of the 640 entries; 4 partial top-20s merged in
// LDS. (v1 was an 8-block launch -- 3% of the device, 640 serial loads.)
// =====================================================================
__global__ void __launch_bounds__(256) k_merge20(
    const float* __restrict__ cand_val, const int* __restrict__ cand_idx,
    int* __restrict__ idx20)
{
  __shared__ float lv[64 * 80];
  __shared__ int   li[64 * 80];
  const int rl = threadIdx.x >> 2, qq = threadIdx.x & 3;
  const int row = blockIdx.x * 64 + rl;

  float tv[CAND]; int ti[CAND];
#pragma unroll
  for (int j = 0; j < CAND; ++j) { tv[j] = -3.0e38f; ti[j] = 0; }
  const int m0 = qq * 160;
  for (int m = m0; m < m0 + 160; ++m) {
    const float s = cand_val[(size_t)m * BATCH + row];
    if (s > tv[CAND - 1]) {
      const int gi = cand_idx[(size_t)m * BATCH + row];
      topk_ins<CAND>(tv, ti, s, gi);
    }
  }
#pragma unroll
  for (int j = 0; j < CAND; ++j) {
    lv[rl * 80 + qq * CAND + j] = tv[j];
    li[rl * 80 + qq * CAND + j] = ti[j];
  }
  __syncthreads();
  if (qq == 0) {
    float fv[CAND]; int fi[CAND];
#pragma unroll
    for (int j = 0; j < CAND; ++j) { fv[j] = -3.0e38f; fi[j] = 0; }
    for (int m = 0; m < 80; ++m) {
      const float s = lv[rl * 80 + m];
      if (s > fv[CAND - 1]) topk_ins<CAND>(fv, fi, s, li[rl * 80 + m]);
    }
#pragma unroll
    for (int j = 0; j < CAND; ++j) idx20[row * CAND + j] = fi[j];
  }
}

// =====================================================================
// K3: exact fp64 rescore of 20 candidates -> final top-10 set.
// One wave per batch row.
// =====================================================================
__global__ void __launch_bounds__(256) k_rescore(
    const float* __restrict__ query, const float* __restrict__ memory,
    const int* __restrict__ idx20, int* __restrict__ idx10)
{
  const int w = threadIdx.x >> 6, l = threadIdx.x & 63;
  const int b = blockIdx.x * 4 + w;
  const float* qp = query + (size_t)b * EMB + l * 16;
  float q[16];
#pragma unroll
  for (int j = 0; j < 4; ++j) {
    const f32x4 v = *(const f32x4*)(qp + 4 * j);
#pragma unroll
    for (int i = 0; i < 4; ++i) q[j * 4 + i] = v[i];
  }
  double sc[CAND];
#pragma unroll
  for (int cc = 0; cc < CAND; ++cc) {
    const int mi = idx20[b * CAND + cc];
    const float* mp = memory + (size_t)mi * EMB + l * 16;
    double s = 0.0;
#pragma unroll
    for (int j = 0; j < 4; ++j) {
      const f32x4 v = *(const f32x4*)(mp + 4 * j);
#pragma unroll
      for (int i = 0; i < 4; ++i) s += (double)q[j * 4 + i] * (double)v[i];
    }
#pragma unroll
    for (int o = 1; o < 64; o <<= 1) s += __shfl_xor(s, o);
    sc[cc] = s;
  }
  if (l == 0) {
    unsigned used = 0;
#pragma unroll
    for (int j = 0; j < TOPK; ++j) {
      double best = -1.0e300; int bi = 0;
#pragma unroll
      for (int cc = 0; cc < CAND; ++cc)
        if (!((used >> cc) & 1u) && sc[cc] > best) { best = sc[cc]; bi = cc; }
      used |= 1u << bi;
      idx10[b * TOPK + j] = idx20[b * CAND + bi];
    }
  }
}

// =====================================================================
// K4: fp16 BT-GEMM, head-batched via blockIdx.z.
// C[m][ccol+n] = sum_k A[m*astr+acol+k]*Bt[n*1024+bcol+k] (+ bias[n]);
// out to fp16 (outH) or fp32 (outF). Per-z offsets: acol+=z*aoffz,
// bcol+=z*boffz, ccol+=z*coffz, bias+=z*biasoffz.
// grid (N/128, M/128, Z), 256 threads, BK=64.
// =====================================================================
__global__ void __launch_bounds__(256) k_gemm16(
    const h16* __restrict__ A, int astr, int acol, int aoffz,
    const h16* __restrict__ Bt, int bcol, int boffz,
    const float* __restrict__ bias, int biasoffz,
    h16* __restrict__ outH, float* __restrict__ outF,
    int cstr, int ccol, int coffz, int nkt)
{
  const int z = blockIdx.z;
  acol += z * aoffz; bcol += z * boffz; ccol += z * coffz;
  const float* bp = bias ? bias + z * biasoffz : nullptr;

  const int c0 = blockIdx.x * 128, r0 = blockIdx.y * 128;
  __shared__ __align__(16) h16 lA[128 * 64], lB[128 * 64];
  const int t = threadIdx.x, w = t >> 6, l = t & 63;
  const int wr = w >> 1, wc = w & 1;
  f32x4 acc[4][4] = {};

  for (int kt = 0; kt < nkt; ++kt) {
    const int k0 = kt * 64;
#pragma unroll
    for (int i = 0; i < 4; ++i) {
      const int ch = w * 256 + i * 64 + l;
      const int row = ch >> 3;
      const int kc = (ch & 7) ^ (row & 7);
      gl_lds16(A  + (size_t)(r0 + row) * astr + acol + k0 + kc * 8,
               lA + (size_t)(w * 256 + i * 64) * 8);
      gl_lds16(Bt + (size_t)(c0 + row) * EMB + bcol + k0 + kc * 8,
               lB + (size_t)(w * 256 + i * 64) * 8);
    }
    __syncthreads();
#pragma unroll
    for (int ks = 0; ks < 2; ++ks) {
      half8 af[4], bfr[4];
#pragma unroll
      for (int mi = 0; mi < 4; ++mi) {
        const int row = wr * 64 + mi * 16 + (l & 15);
        const int slot = (ks * 4 + (l >> 4)) ^ (row & 7);
        af[mi] = *(const half8*)&lA[row * 64 + slot * 8];
      }
#pragma unroll
      for (int ni = 0; ni < 4; ++ni) {
        const int row = wc * 64 + ni * 16 + (l & 15);
        const int slot = (ks * 4 + (l >> 4)) ^ (row & 7);
        bfr[ni] = *(const half8*)&lB[row * 64 + slot * 8];
      }
#pragma unroll
      for (int mi = 0; mi < 4; ++mi)
#pragma unroll
        for (int ni = 0; ni < 4; ++ni)
          acc[mi][ni] = __builtin_amdgcn_mfma_f32_16x16x32_f16(
              af[mi], bfr[ni], acc[mi][ni], 0, 0, 0);
    }
    __syncthreads();
  }
#pragma unroll
  for (int ni = 0; ni < 4; ++ni) {
    const int ncol = c0 + wc * 64 + ni * 16 + (l & 15);
    const float bv = bp ? bp[ncol] : 0.0f;
#pragma unroll
    for (int mi = 0; mi < 4; ++mi)
#pragma unroll
      for (int r = 0; r < 4; ++r) {
        const int grow = r0 + wr * 64 + mi * 16 + (l >> 4) * 4 + r;
        const float v = acc[mi][ni][r] + bv;
        if (outH) outH[(size_t)grow * cstr + ccol + ncol] = (h16)v;
        else      outF[(size_t)grow * cstr + ccol + ncol] = v;
      }
  }
}

// =====================================================================
// K5: attention over all 8 heads, ONLINE softmax (single pass over the
// 10 rows per head). One wave per batch row.
// qtA[b][h*1024+:] holds qt on entry; overwritten with mv per head.
// =====================================================================
__global__ void __launch_bounds__(256) k_attn(
    const float* __restrict__ memory, const int* __restrict__ idx10,
    h16* __restrict__ qtA)
{
  const int w = threadIdx.x >> 6, l = threadIdx.x & 63;
  const int b = blockIdx.x * 4 + w;
  int rows[TOPK];
#pragma unroll
  for (int k = 0; k < TOPK; ++k) rows[k] = idx10[b * TOPK + k];

  for (int h = 0; h < HEADS; ++h) {
    h16* qp = qtA + (size_t)b * (HEADS * EMB) + h * EMB + l * 16;
    const half8 qa = *(const half8*)qp;
    const half8 qb = *(const half8*)(qp + 8);
    float qf[16];
#pragma unroll
    for (int j = 0; j < 8; ++j) { qf[j] = (float)qa[j]; qf[8 + j] = (float)qb[j]; }

    float mrun = -3.0e38f, den = 0.f;
    float acc[16];
#pragma unroll
    for (int j = 0; j < 16; ++j) acc[j] = 0.f;

#pragma unroll
    for (int k = 0; k < TOPK; ++k) {
      const float* mp = memory + (size_t)rows[k] * EMB + l * 16;
      float mv[16]; float p = 0.f;
#pragma unroll
      for (int j = 0; j < 4; ++j) {
        const f32x4 m = *(const f32x4*)(mp + 4 * j);
#pragma unroll
        for (int i = 0; i < 4; ++i) { mv[j * 4 + i] = m[i]; p += qf[j * 4 + i] * m[i]; }
      }
#pragma unroll
      for (int o = 1; o < 64; o <<= 1) p += __shfl_xor(p, o);
      p *= SCALE;
      if (p > mrun) {                    // wave-uniform
        const float rs = __expf(mrun - p);   // first iter: exp(-huge)=0
        den *= rs;
#pragma unroll
        for (int j = 0; j < 16; ++j) acc[j] *= rs;
        mrun = p;
      }
      const float e = __expf(p - mrun);
      den += e;
#pragma unroll
      for (int j = 0; j < 16; ++j) acc[j] += e * mv[j];
    }
    const float inv = 1.0f / den;
    half8 o0, o1;
#pragma unroll
    for (int j = 0; j < 8; ++j) {
      o0[j] = (h16)(acc[j] * inv);
      o1[j] = (h16)(acc[8 + j] * inv);
    }
    *(half8*)qp = o0;
    *(half8*)(qp + 8) = o1;
  }
}

// =====================================================================
extern "C" void kernel_launch(void* const* d_in, const int* in_sizes, int n_in,
                              void* d_out, int out_size, void* d_ws, size_t ws_size,
                              hipStream_t stream)
{
  const float* query  = (const float*)d_in[0];
  const float* memory = (const float*)d_in[1];
  const float* w_q    = (const float*)d_in[2];
  const float* w_k    = (const float*)d_in[3];
  const float* w_v    = (const float*)d_in[4];
  const float* b_q    = (const float*)d_in[5];
  // b_k (d_in[6]) cancels in softmax
  const float* b_v    = (const float*)d_in[7];
  const float* w_o    = (const float*)d_in[8];
  const float* b_o    = (const float*)d_in[9];

  char* ws = (char*)d_ws;
  float* cand_val = (float*)(ws + 0);            //  5,242,880
  int*   cand_idx = (int*)  (ws + 5242880);      //  5,242,880
  int*   idx20    = (int*)  (ws + 10485760);     //    163,840
  int*   idx10    = (int*)  (ws + 10649600);     //     81,920
  h16*   qH       = (h16*)  (ws + 10731520);     //  4,194,304
  h16*   wqH      = (h16*)  (ws + 14925824);     //  2,097,152
  h16*   wkTH     = (h16*)  (ws + 17022976);     //  2,097,152
  h16*   wvH      = (h16*)  (ws + 19120128);     //  2,097,152
  h16*   woH      = (h16*)  (ws + 21217280);     //  2,097,152
  h16*   qpH      = (h16*)  (ws + 23314432);     //  4,194,304
  h16*   qtA      = (h16*)  (ws + 27508736);     // 33,554,432 (qt then mv)
  h16*   ctxH     = (h16*)  (ws + 61063168);     //  4,194,304  -> end 65,257,472
  h16*   memH     = (h16*)  (ws + 65257472);     // 204,800,000 -> end 270,057,472

  const bool fast = ws_size >= 270057472ULL;     // constant per deployment

  // conversions
  if (fast) k_f2hW<<<8192, 256, 0, stream>>>(memory, memH, 12800000L);
  k_convA<<<5120, 256, 0, stream>>>(query, w_q, w_v, w_o, qH, wqH, wvH, woH);
  k_f2hT<<<dim3(16, 16), 256, 0, stream>>>(w_k, wkTH);

  // retrieval: coarse fp16 scores + per-chunk top-10
  if (fast) k_sim_h  <<<dim3(8, CHUNKS), 512, 0, stream>>>(qH, memH, cand_val, cand_idx);
  else      k_sim_f32<<<dim3(CHUNKS, 16), 256, 0, stream>>>(query, memory, cand_val, cand_idx);
  // coarse top-20, then exact fp64 rescore -> final top-10 set
  k_merge20<<<BATCH / 64, 256, 0, stream>>>(cand_val, cand_idx, idx20);
  k_rescore<<<BATCH / 4, 256, 0, stream>>>(query, memory, idx20, idx10);

  // q projection: qpH = query @ w_q^T + b_q
  k_gemm16<<<dim3(8, 16), 256, 0, stream>>>(qH, EMB, 0, 0, wqH, 0, 0,
                                            b_q, 0, qpH, nullptr, EMB, 0, 0, 16);
  // per-head qt (all 8 heads in one launch):
  // qtA[b][h*1024+e] = sum_d qpH[b][h*128+d] * w_k[h*128+d][e]
  k_gemm16<<<dim3(8, 16, 8), 256, 0, stream>>>(qpH, EMB, 0, HDIM, wkTH, 0, HDIM,
                                               nullptr, 0, qtA, nullptr,
                                               HEADS * EMB, 0, EMB, 2);
  // attention (scores vs fp32 memory, online softmax, mv in place)
  k_attn<<<BATCH / 4, 256, 0, stream>>>(memory, idx10, qtA);
  // per-head ctx (all 8 heads in one launch):
  // ctxH[b][h*128+d] = sum_e mv[b][h*1024+e]*w_v[h*128+d][e] + b_v
  k_gemm16<<<dim3(1, 16, 8), 256, 0, stream>>>(qtA, HEADS * EMB, 0, EMB,
                                               wvH, 0, HDIM * EMB,
                                               b_v, HDIM, ctxH, nullptr,
                                               EMB, 0, HDIM, 16);
  // output projection -> fp32 d_out
  k_gemm16<<<dim3(8, 16), 256, 0, stream>>>(ctxH, EMB, 0, 0, woH, 0, 0,
                                            b_o, 0, nullptr, (float*)d_out,
                                            EMB, 0, 0, 16);
}